// Round 1
// baseline (3488.333 us; speedup 1.0000x reference)
//
#include <hip/hip_runtime.h>

#define BATCH 100000
#define SEQ   28
#define NIN   28
#define HID   64
#define NOUT  10

// fast sigmoid/tanh via hardware exp (v_exp_f32); saturation behavior is
// correct at +-inf (rcp(inf)=0).
__device__ __forceinline__ float sigmoid_(float x) {
    return 1.0f / (1.0f + __expf(-x));
}
__device__ __forceinline__ float tanh_(float x) {
    return 1.0f - 2.0f / (1.0f + __expf(2.0f * x));
}

__global__ __launch_bounds__(256) void gru_fp32_kernel(
    const float* __restrict__ X,     // [B, S, IN]
    const float* __restrict__ Wih,   // [3H, IN]  rows: r(0..63), z(64..127), n(128..191)
    const float* __restrict__ Whh,   // [3H, H]
    const float* __restrict__ bih,   // [3H]
    const float* __restrict__ bhh,   // [3H]
    const float* __restrict__ Wout,  // [OUT, H]
    const float* __restrict__ bout,  // [OUT]
    float* __restrict__ out)         // [B, OUT]
{
    // Private per-thread column; lane-consecutive addresses -> conflict-free.
    // Used only to allow dynamic indexing by j without register spills.
    __shared__ float hn_buf[HID][256];

    const int tid = threadIdx.x;
    const long row = (long)blockIdx.x * 256 + tid;
    if (row >= BATCH) return;

    float h[HID];
#pragma unroll
    for (int k = 0; k < HID; ++k) h[k] = 0.0f;
#pragma unroll
    for (int k = 0; k < HID; ++k) hn_buf[k][tid] = 0.0f;

    const float* xrow = X + row * (long)(SEQ * NIN);

    for (int s = 0; s < SEQ; ++s) {
        // x_t: 28 floats = 7 float4 loads (112B contiguous, 16B aligned)
        float x[NIN];
        const float4* xp = (const float4*)(xrow + s * NIN);
#pragma unroll
        for (int q = 0; q < NIN / 4; ++q) {
            float4 v = xp[q];
            x[4 * q + 0] = v.x; x[4 * q + 1] = v.y;
            x[4 * q + 2] = v.z; x[4 * q + 3] = v.w;
        }

        // j rolled (keeps icache small); k loops unrolled; weight addresses
        // are wave-uniform -> scalar-cache s_loads, FMAs take SGPR operand.
        for (int j = 0; j < HID; ++j) {
            float ar  = bih[j]           + bhh[j];
            float az  = bih[HID + j]     + bhh[HID + j];
            float ani = bih[2 * HID + j];
            float anh = bhh[2 * HID + j];

            const float* wr = Wih + j * NIN;
            const float* wz = Wih + (HID + j) * NIN;
            const float* wn = Wih + (2 * HID + j) * NIN;
#pragma unroll
            for (int k = 0; k < NIN; ++k) {
                const float xv = x[k];
                ar  = fmaf(wr[k], xv, ar);
                az  = fmaf(wz[k], xv, az);
                ani = fmaf(wn[k], xv, ani);
            }

            const float* ur = Whh + j * HID;
            const float* uz = Whh + (HID + j) * HID;
            const float* un = Whh + (2 * HID + j) * HID;
#pragma unroll
            for (int k = 0; k < HID; ++k) {
                const float hv = h[k];
                ar  = fmaf(ur[k], hv, ar);
                az  = fmaf(uz[k], hv, az);
                anh = fmaf(un[k], hv, anh);
            }

            const float r = sigmoid_(ar);
            const float z = sigmoid_(az);
            const float n = tanh_(fmaf(r, anh, ani));

            // h[j] with dynamic j: read the old value from the LDS column
            // (it still holds h(s)[j]), then overwrite with h(s+1)[j].
            const float hj = hn_buf[j][tid];
            hn_buf[j][tid] = fmaf(z, hj - n, n);   // (1-z)*n + z*h
        }

        // pull h(s+1) back into static registers
#pragma unroll
        for (int k = 0; k < HID; ++k) h[k] = hn_buf[k][tid];
    }

    // output head: out = h @ Wout^T + bout
#pragma unroll
    for (int o = 0; o < NOUT; ++o) {
        float acc = bout[o];
        const float* wo = Wout + o * HID;
#pragma unroll
        for (int k = 0; k < HID; ++k) acc = fmaf(wo[k], h[k], acc);
        out[row * NOUT + o] = acc;
    }
}

extern "C" void kernel_launch(void* const* d_in, const int* in_sizes, int n_in,
                              void* d_out, int out_size, void* d_ws, size_t ws_size,
                              hipStream_t stream) {
    const float* X    = (const float*)d_in[0];
    const float* Wih  = (const float*)d_in[1];
    const float* Whh  = (const float*)d_in[2];
    const float* bih  = (const float*)d_in[3];
    const float* bhh  = (const float*)d_in[4];
    const float* Wout = (const float*)d_in[5];
    const float* bout = (const float*)d_in[6];
    float* out = (float*)d_out;

    const int blocks = (BATCH + 255) / 256;
    gru_fp32_kernel<<<blocks, 256, 0, stream>>>(X, Wih, Whh, bih, bhh, Wout, bout, out);
}

// Round 2
// 1516.121 us; speedup vs baseline: 2.3008x; 2.3008x over previous
//
#include <hip/hip_runtime.h>
#include <hip/hip_bf16.h>

#define BATCH 100000
#define SEQ   28
#define NIN   28
#define HID   64
#define NOUT  10
#define BM    128
#define NBLK  ((BATCH + BM - 1) / BM)

typedef short bf8 __attribute__((ext_vector_type(8)));   // 8 bf16 (4 VGPRs)
typedef short bf4 __attribute__((ext_vector_type(4)));
typedef float f4  __attribute__((ext_vector_type(4)));

__device__ __forceinline__ short f2bf(float f) {
    __hip_bfloat16 b = __float2bfloat16(f);   // RNE
    return *reinterpret_cast<short*>(&b);
}
__device__ __forceinline__ float sig_(float x) {
    return __builtin_amdgcn_rcpf(1.0f + __expf(-x));
}
__device__ __forceinline__ float tanh_(float x) {
    return 1.0f - 2.0f * __builtin_amdgcn_rcpf(1.0f + __expf(2.0f * x));
}

// Per block: 128 batch rows, 4 waves, wave w owns rows 32w..32w+31.
// Per step: gates[32x192] = x_t[32x32pad] @ Wih^T  +  h[32x64] @ Whh^T  (+bias)
// via 16x16x32 bf16 MFMA. r,z share accumulators (i_r+h_r sums); n keeps
// i_n / h_n separate (PyTorch GRU: n = tanh(i_n + r*h_n)).
// No __syncthreads in the step loop: all data deps are wave-local.
__global__ __launch_bounds__(256, 2) void gru_mfma_kernel(
    const float* __restrict__ X,     // [B, S, IN]
    const float* __restrict__ Wih,   // [192, 28]
    const float* __restrict__ Whh,   // [192, 64]
    const float* __restrict__ bih,   // [192]
    const float* __restrict__ bhh,   // [192]
    const float* __restrict__ Wout,  // [10, 64]
    const float* __restrict__ bout,  // [10]
    float* __restrict__ out)         // [B, 10]
{
    // B-fragment-layout weight caches (value for lane: n=lane&15, k=quad*8+j)
    __shared__ short sBih[12 * 64 * 8];        // [ctile][lane][8]   12 KB
    __shared__ short sBhh[12 * 2 * 64 * 8];    // [ctile][kk][lane][8] 24 KB
    __shared__ short sBout[2 * 64 * 8];        // [kk][lane][8]       2 KB
    __shared__ short sH[BM][68];               // h, padded stride    17 KB

    const int tid = threadIdx.x;

    // ---- one-time setup: global fp32 weights -> bf16 fragments in LDS ----
    for (int idx = tid; idx < 12 * 64; idx += 256) {
        int c = idx >> 6, ln = idx & 63;
        int g = 16 * c + (ln & 15), k0 = (ln >> 4) * 8;
#pragma unroll
        for (int j = 0; j < 8; ++j) {
            int k = k0 + j;
            sBih[idx * 8 + j] = f2bf(k < NIN ? Wih[g * NIN + k] : 0.0f);
        }
    }
    for (int idx = tid; idx < 12 * 2 * 64; idx += 256) {
        int c = idx >> 7, kk = (idx >> 6) & 1, ln = idx & 63;
        int g = 16 * c + (ln & 15), k0 = kk * 32 + (ln >> 4) * 8;
#pragma unroll
        for (int j = 0; j < 8; ++j)
            sBhh[idx * 8 + j] = f2bf(Whh[g * HID + k0 + j]);
    }
    for (int idx = tid; idx < 2 * 64; idx += 256) {
        int kk = idx >> 6, ln = idx & 63;
        int n = ln & 15, k0 = kk * 32 + (ln >> 4) * 8;
#pragma unroll
        for (int j = 0; j < 8; ++j)
            sBout[idx * 8 + j] = f2bf(n < NOUT ? Wout[n * HID + k0 + j] : 0.0f);
    }
    for (int idx = tid; idx < BM * 68 / 2; idx += 256)
        ((int*)sH)[idx] = 0;                  // h0 = 0

    const int lane = tid & 63, w = tid >> 6;
    const int q = lane >> 4, l15 = lane & 15;

    // per-lane bias registers (depend only on gate col = 16c + l15)
    float brz[8], bni[4], bnh[4];
#pragma unroll
    for (int c = 0; c < 8; ++c) brz[c] = bih[16 * c + l15] + bhh[16 * c + l15];
#pragma unroll
    for (int c = 0; c < 4; ++c) {
        bni[c] = bih[128 + 16 * c + l15];
        bnh[c] = bhh[128 + 16 * c + l15];
    }
    const float bo = (l15 < NOUT) ? bout[l15] : 0.0f;

    __syncthreads();

    const int row0 = blockIdx.x * BM + 32 * w;   // this wave's first batch row
    f4 hreg[2][4];                               // h in C-layout, fp32
#pragma unroll
    for (int t = 0; t < 2; ++t)
#pragma unroll
        for (int c = 0; c < 4; ++c) hreg[t][c] = (f4){0.f, 0.f, 0.f, 0.f};

#pragma unroll 1
    for (int s = 0; s < SEQ; ++s) {
        // A-frags for x_t: lane = features q*8..q*8+7 of row row0+16t+l15
        bf8 xa[2];
#pragma unroll
        for (int t = 0; t < 2; ++t) {
            int r = row0 + 16 * t + l15;
            if (r > BATCH - 1) r = BATCH - 1;
            const float* p = X + (long)r * (SEQ * NIN) + s * NIN + q * 8;
            float4 v0 = *(const float4*)p;
            float4 v1 = make_float4(0.f, 0.f, 0.f, 0.f);
            if (q < 3) v1 = *(const float4*)(p + 4);   // features 28..31 = 0-pad
            bf8 f;
            f[0] = f2bf(v0.x); f[1] = f2bf(v0.y); f[2] = f2bf(v0.z); f[3] = f2bf(v0.w);
            f[4] = f2bf(v1.x); f[5] = f2bf(v1.y); f[6] = f2bf(v1.z); f[7] = f2bf(v1.w);
            xa[t] = f;
        }

        // accumulators, bias-initialized
        f4 arz[2][8], axn[2][4], ahn[2][4];
#pragma unroll
        for (int t = 0; t < 2; ++t) {
#pragma unroll
            for (int c = 0; c < 8; ++c) {
                f4 v = {brz[c], brz[c], brz[c], brz[c]};
                arz[t][c] = v;
            }
#pragma unroll
            for (int c = 0; c < 4; ++c) {
                f4 vi = {bni[c], bni[c], bni[c], bni[c]};
                f4 vh = {bnh[c], bnh[c], bnh[c], bnh[c]};
                axn[t][c] = vi;
                ahn[t][c] = vh;
            }
        }

        // Gx: x_t @ Wih^T  (K=32, one k-step)
#pragma unroll
        for (int c = 0; c < 12; ++c) {
            bf8 bfrag = *(const bf8*)&sBih[(c * 64 + lane) * 8];
#pragma unroll
            for (int t = 0; t < 2; ++t) {
                if (c < 8)
                    arz[t][c] = __builtin_amdgcn_mfma_f32_16x16x32_bf16(xa[t], bfrag, arz[t][c], 0, 0, 0);
                else
                    axn[t][c - 8] = __builtin_amdgcn_mfma_f32_16x16x32_bf16(xa[t], bfrag, axn[t][c - 8], 0, 0, 0);
            }
        }

        // Gh: h @ Whh^T  (K=64, two k-steps); h read from sH (A-layout via [row][col])
#pragma unroll
        for (int kk = 0; kk < 2; ++kk) {
            bf8 ha[2];
#pragma unroll
            for (int t = 0; t < 2; ++t) {
                const short* p = &sH[32 * w + 16 * t + l15][kk * 32 + q * 8];
                bf4 lo = *(const bf4*)p;
                bf4 hi = *(const bf4*)(p + 4);
                bf8 f;
                f[0] = lo[0]; f[1] = lo[1]; f[2] = lo[2]; f[3] = lo[3];
                f[4] = hi[0]; f[5] = hi[1]; f[6] = hi[2]; f[7] = hi[3];
                ha[t] = f;
            }
#pragma unroll
            for (int c = 0; c < 12; ++c) {
                bf8 bfrag = *(const bf8*)&sBhh[((c * 2 + kk) * 64 + lane) * 8];
#pragma unroll
                for (int t = 0; t < 2; ++t) {
                    if (c < 8)
                        arz[t][c] = __builtin_amdgcn_mfma_f32_16x16x32_bf16(ha[t], bfrag, arz[t][c], 0, 0, 0);
                    else
                        ahn[t][c - 8] = __builtin_amdgcn_mfma_f32_16x16x32_bf16(ha[t], bfrag, ahn[t][c - 8], 0, 0, 0);
                }
            }
        }

        // activations, all in-lane (C layout: row = 4q+e, col = 16hc+l15)
#pragma unroll
        for (int t = 0; t < 2; ++t) {
#pragma unroll
            for (int hc = 0; hc < 4; ++hc) {
                f4 rv = arz[t][hc], zv = arz[t][hc + 4];
                f4 xnv = axn[t][hc], hnv = ahn[t][hc], hp = hreg[t][hc];
                f4 hnew;
#pragma unroll
                for (int e = 0; e < 4; ++e) {
                    float r = sig_(rv[e]);
                    float z = sig_(zv[e]);
                    float n = tanh_(fmaf(r, hnv[e], xnv[e]));
                    float h = fmaf(z, hp[e] - n, n);   // (1-z)*n + z*h
                    hnew[e] = h;
                    sH[32 * w + 16 * t + 4 * q + e][16 * hc + l15] = f2bf(h);
                }
                hreg[t][hc] = hnew;
            }
        }
    }

    // head: out = h @ Wout^T + bout  (one 16-col tile, K=64)
    f4 ao[2];
#pragma unroll
    for (int t = 0; t < 2; ++t) { f4 v = {bo, bo, bo, bo}; ao[t] = v; }
#pragma unroll
    for (int kk = 0; kk < 2; ++kk) {
        bf8 bfrag = *(const bf8*)&sBout[(kk * 64 + lane) * 8];
#pragma unroll
        for (int t = 0; t < 2; ++t) {
            const short* p = &sH[32 * w + 16 * t + l15][kk * 32 + q * 8];
            bf4 lo = *(const bf4*)p;
            bf4 hi = *(const bf4*)(p + 4);
            bf8 f;
            f[0] = lo[0]; f[1] = lo[1]; f[2] = lo[2]; f[3] = lo[3];
            f[4] = hi[0]; f[5] = hi[1]; f[6] = hi[2]; f[7] = hi[3];
            ao[t] = __builtin_amdgcn_mfma_f32_16x16x32_bf16(f, bfrag, ao[t], 0, 0, 0);
        }
    }
#pragma unroll
    for (int t = 0; t < 2; ++t)
#pragma unroll
        for (int e = 0; e < 4; ++e) {
            int r = row0 + 16 * t + 4 * q + e;
            if (r < BATCH && l15 < NOUT) out[r * NOUT + l15] = ao[t][e];
        }
}

extern "C" void kernel_launch(void* const* d_in, const int* in_sizes, int n_in,
                              void* d_out, int out_size, void* d_ws, size_t ws_size,
                              hipStream_t stream) {
    const float* X    = (const float*)d_in[0];
    const float* Wih  = (const float*)d_in[1];
    const float* Whh  = (const float*)d_in[2];
    const float* bih  = (const float*)d_in[3];
    const float* bhh  = (const float*)d_in[4];
    const float* Wout = (const float*)d_in[5];
    const float* bout = (const float*)d_in[6];
    float* out = (float*)d_out;

    gru_mfma_kernel<<<NBLK, 256, 0, stream>>>(X, Wih, Whh, bih, bhh, Wout, bout, out);
}

// Round 3
// 871.495 us; speedup vs baseline: 4.0027x; 1.7397x over previous
//
#include <hip/hip_runtime.h>
#include <hip/hip_bf16.h>

#define BATCH 100000
#define SEQ   28
#define NIN   28
#define HID   64
#define NOUT  10
#define BM    64
#define NBLK  ((BATCH + BM - 1) / BM)
#define LOG2E 1.4426950408889634f

typedef short bf8 __attribute__((ext_vector_type(8)));   // 8 bf16 (4 VGPRs)
typedef short bf4 __attribute__((ext_vector_type(4)));
typedef float f4  __attribute__((ext_vector_type(4)));

__device__ __forceinline__ short f2bf(float f) {
    __hip_bfloat16 b = __float2bfloat16(f);   // RNE
    return *reinterpret_cast<short*>(&b);
}

// Per block: 64 batch rows, 4 waves, wave w owns rows 16w..16w+15.
// gates[16x192] = x_t[16x32pad] @ Wih'^T + h[16x64] @ Whh'^T (+bias'), where
// the r,z weight rows are pre-scaled by -log2e and the n rows by 2*log2e so
// sigmoid(x) = rcp(1+exp2(u)) and tanh(y) = 1-2*rcp(1+exp2(y')) need no
// in-loop scaling (exp2/rcp are the quarter-rate floor).
// No __syncthreads in the step loop: all data deps are wave-local.
__global__ __launch_bounds__(256, 2) void gru_mfma2_kernel(
    const float* __restrict__ X,     // [B, S, IN]
    const float* __restrict__ Wih,   // [192, 28]
    const float* __restrict__ Whh,   // [192, 64]
    const float* __restrict__ bih,   // [192]
    const float* __restrict__ bhh,   // [192]
    const float* __restrict__ Wout,  // [10, 64]
    const float* __restrict__ bout,  // [10]
    float* __restrict__ out)         // [B, 10]
{
    // B-fragment caches (lane value: n=lane&15, k=(lane>>4)*8+j)
    __shared__ short sBih[12 * 64 * 8];        // 12 KB
    __shared__ short sBhh[12 * 2 * 64 * 8];    // 24 KB
    __shared__ short sBout[2 * 64 * 8];        // 2 KB
    __shared__ short sH[BM][66];               // 8.25 KB, padded stride

    const int tid = threadIdx.x;

    // ---- one-time: fp32 weights -> pre-scaled bf16 B-fragments in LDS ----
    for (int idx = tid; idx < 12 * 64; idx += 256) {
        int c = idx >> 6, ln = idx & 63;
        int g = 16 * c + (ln & 15), k0 = (ln >> 4) * 8;
        float sc = (c < 8) ? -LOG2E : 2.0f * LOG2E;
#pragma unroll
        for (int j = 0; j < 8; ++j) {
            int k = k0 + j;
            sBih[idx * 8 + j] = f2bf(k < NIN ? sc * Wih[g * NIN + k] : 0.0f);
        }
    }
    for (int idx = tid; idx < 12 * 2 * 64; idx += 256) {
        int c = idx >> 7, kk = (idx >> 6) & 1, ln = idx & 63;
        int g = 16 * c + (ln & 15), k0 = kk * 32 + (ln >> 4) * 8;
        float sc = (c < 8) ? -LOG2E : 2.0f * LOG2E;
#pragma unroll
        for (int j = 0; j < 8; ++j)
            sBhh[idx * 8 + j] = f2bf(sc * Whh[g * HID + k0 + j]);
    }
    for (int idx = tid; idx < 2 * 64; idx += 256) {
        int kk = idx >> 6, ln = idx & 63;
        int n = ln & 15, k0 = kk * 32 + (ln >> 4) * 8;
#pragma unroll
        for (int j = 0; j < 8; ++j)
            sBout[idx * 8 + j] = f2bf(n < NOUT ? Wout[n * HID + k0 + j] : 0.0f);
    }
    for (int idx = tid; idx < BM * 66 / 2; idx += 256)
        ((int*)sH)[idx] = 0;                  // h0 = 0

    const int lane = tid & 63, w = tid >> 6;
    const int q = lane >> 4, l15 = lane & 15;

    // pre-scaled per-lane biases (gate col = 16c + l15)
    float brz[8], bni[4], bnh[4];
#pragma unroll
    for (int c = 0; c < 8; ++c)
        brz[c] = -LOG2E * (bih[16 * c + l15] + bhh[16 * c + l15]);
#pragma unroll
    for (int c = 0; c < 4; ++c) {
        bni[c] = 2.0f * LOG2E * bih[128 + 16 * c + l15];
        bnh[c] = 2.0f * LOG2E * bhh[128 + 16 * c + l15];
    }
    const float bo = (l15 < NOUT) ? bout[l15] : 0.0f;

    __syncthreads();

    const int row0 = blockIdx.x * BM + 16 * w;
    int xr = row0 + l15;                      // this lane's batch row
    if (xr > BATCH - 1) xr = BATCH - 1;       // clamp (writes guarded later)
    const float* xbase = X + (long)xr * (SEQ * NIN) + q * 8;

    f4 hreg[4];                               // h in C-layout, fp32
#pragma unroll
    for (int c = 0; c < 4; ++c) hreg[c] = (f4){0.f, 0.f, 0.f, 0.f};

    // preload x for s=0
    float4 v0n = *(const float4*)xbase;
    float4 v1n = make_float4(0.f, 0.f, 0.f, 0.f);
    if (q < 3) v1n = *(const float4*)(xbase + 4);
    bf8 xa;
    xa[0] = f2bf(v0n.x); xa[1] = f2bf(v0n.y); xa[2] = f2bf(v0n.z); xa[3] = f2bf(v0n.w);
    xa[4] = f2bf(v1n.x); xa[5] = f2bf(v1n.y); xa[6] = f2bf(v1n.z); xa[7] = f2bf(v1n.w);

#pragma unroll 1
    for (int s = 0; s < SEQ; ++s) {
        // accumulators, bias-initialized (free vs zero-init)
        f4 arz[8], axn[4], ahn[4];
#pragma unroll
        for (int c = 0; c < 8; ++c) { f4 v = {brz[c], brz[c], brz[c], brz[c]}; arz[c] = v; }
#pragma unroll
        for (int c = 0; c < 4; ++c) {
            f4 vi = {bni[c], bni[c], bni[c], bni[c]};
            f4 vh = {bnh[c], bnh[c], bnh[c], bnh[c]};
            axn[c] = vi; ahn[c] = vh;
        }

        // Gh first (h ready from prev step's LDS writes; x prefetch in flight)
#pragma unroll
        for (int kk = 0; kk < 2; ++kk) {
            const short* p = &sH[16 * w + l15][kk * 32 + q * 8];
            bf4 lo = *(const bf4*)p;
            bf4 hi = *(const bf4*)(p + 4);
            bf8 ha;
            ha[0] = lo[0]; ha[1] = lo[1]; ha[2] = lo[2]; ha[3] = lo[3];
            ha[4] = hi[0]; ha[5] = hi[1]; ha[6] = hi[2]; ha[7] = hi[3];
#pragma unroll
            for (int c = 0; c < 12; ++c) {
                bf8 bfrag = *(const bf8*)&sBhh[((c * 2 + kk) * 64 + lane) * 8];
                if (c < 8)
                    arz[c] = __builtin_amdgcn_mfma_f32_16x16x32_bf16(ha, bfrag, arz[c], 0, 0, 0);
                else
                    ahn[c - 8] = __builtin_amdgcn_mfma_f32_16x16x32_bf16(ha, bfrag, ahn[c - 8], 0, 0, 0);
            }
        }

        // Gx
#pragma unroll
        for (int c = 0; c < 12; ++c) {
            bf8 bfrag = *(const bf8*)&sBih[(c * 64 + lane) * 8];
            if (c < 8)
                arz[c] = __builtin_amdgcn_mfma_f32_16x16x32_bf16(xa, bfrag, arz[c], 0, 0, 0);
            else
                axn[c - 8] = __builtin_amdgcn_mfma_f32_16x16x32_bf16(xa, bfrag, axn[c - 8], 0, 0, 0);
        }

        // prefetch x for step s+1 (latency hidden under activations)
        {
            int sn = (s < SEQ - 1) ? s + 1 : s;
            const float* p = xbase + sn * NIN;
            v0n = *(const float4*)p;
            if (q < 3) v1n = *(const float4*)(p + 4);
        }

        // activations, all in-lane (C layout: row=4q+e, col=16hc+l15)
#pragma unroll
        for (int hc = 0; hc < 4; ++hc) {
            f4 hnew;
#pragma unroll
            for (int e = 0; e < 4; ++e) {
                float r = __builtin_amdgcn_rcpf(1.0f + __builtin_amdgcn_exp2f(arz[hc][e]));
                float z = __builtin_amdgcn_rcpf(1.0f + __builtin_amdgcn_exp2f(arz[hc + 4][e]));
                float y = fmaf(r, ahn[hc][e], axn[hc][e]);
                float t = __builtin_amdgcn_rcpf(1.0f + __builtin_amdgcn_exp2f(y));
                float n = fmaf(-2.0f, t, 1.0f);
                float h = fmaf(z, hreg[hc][e] - n, n);   // (1-z)*n + z*h
                hnew[e] = h;
                sH[16 * w + 4 * q + e][16 * hc + l15] = f2bf(h);
            }
            hreg[hc] = hnew;
        }

        // convert prefetched x (vmcnt wait lands here, after activations)
        xa[0] = f2bf(v0n.x); xa[1] = f2bf(v0n.y); xa[2] = f2bf(v0n.z); xa[3] = f2bf(v0n.w);
        xa[4] = f2bf(v1n.x); xa[5] = f2bf(v1n.y); xa[6] = f2bf(v1n.z); xa[7] = f2bf(v1n.w);
    }

    // head: out = h @ Wout^T + bout  (one 16-col tile, K=64)
    f4 ao = {bo, bo, bo, bo};
#pragma unroll
    for (int kk = 0; kk < 2; ++kk) {
        const short* p = &sH[16 * w + l15][kk * 32 + q * 8];
        bf4 lo = *(const bf4*)p;
        bf4 hi = *(const bf4*)(p + 4);
        bf8 f;
        f[0] = lo[0]; f[1] = lo[1]; f[2] = lo[2]; f[3] = lo[3];
        f[4] = hi[0]; f[5] = hi[1]; f[6] = hi[2]; f[7] = hi[3];
        bf8 bfrag = *(const bf8*)&sBout[(kk * 64 + lane) * 8];
        ao = __builtin_amdgcn_mfma_f32_16x16x32_bf16(f, bfrag, ao, 0, 0, 0);
    }
#pragma unroll
    for (int e = 0; e < 4; ++e) {
        int r = row0 + 4 * q + e;
        if (r < BATCH && l15 < NOUT) out[r * NOUT + l15] = ao[e];
    }
}

extern "C" void kernel_launch(void* const* d_in, const int* in_sizes, int n_in,
                              void* d_out, int out_size, void* d_ws, size_t ws_size,
                              hipStream_t stream) {
    const float* X    = (const float*)d_in[0];
    const float* Wih  = (const float*)d_in[1];
    const float* Whh  = (const float*)d_in[2];
    const float* bih  = (const float*)d_in[3];
    const float* bhh  = (const float*)d_in[4];
    const float* Wout = (const float*)d_in[5];
    const float* bout = (const float*)d_in[6];
    float* out = (float*)d_out;

    gru_mfma2_kernel<<<NBLK, 256, 0, stream>>>(X, Wih, Whh, bih, bhh, Wout, bout, out);
}